// Round 8
// baseline (420.523 us; speedup 1.0000x reference)
//
#include <hip/hip_runtime.h>
#include <hip/hip_fp16.h>

#define NN 8192
#define INF 128
#define OUTF 64
#define KK 2
#define NROWS (KK * NN)
#define MAXD 256
#define WH_RPB 16
#define WPAD 130

typedef float floatx4 __attribute__((ext_vector_type(4)));

// ---- Kernel 1: Wh = x@W -> WhI fp16 [j][k*64+f]; Wh1 fp32 [k][N]; W2I fp32 [j][k]
// Register-blocked: each wave computes 4 rows per pass; one per-lane W b128 read
// is reused across 4 broadcast x reads (broadcasts are LDS-conflict-free).
__global__ __launch_bounds__(256) void wh_kernel(
    const float* __restrict__ x, const float* __restrict__ weight,
    const float* __restrict__ a,
    __half* __restrict__ WhI, float* __restrict__ Wh1, float* __restrict__ W2I)
{
    __shared__ float sWt[OUTF * WPAD];     // transposed W: [f][c], pad 130 (33 KB)
    __shared__ float sx[WH_RPB * INF];     // 8 KB
    int tid = threadIdx.x;
    for (int idx = tid; idx < INF * OUTF; idx += 256) {
        int c = idx >> 6, f = idx & 63;    // weight[c][f] row-major [128][64]
        sWt[f * WPAD + c] = weight[idx];
    }
    int rowBase = blockIdx.x * WH_RPB;     // global row in [0, 16384)
    const float4* xb = (const float4*)(x + (size_t)rowBase * INF);
#pragma unroll
    for (int idx = tid; idx < (WH_RPB * INF) / 4; idx += 256)
        ((float4*)sx)[idx] = xb[idx];
    __syncthreads();

    int wave = tid >> 6, lane = tid & 63;
    float a1 = a[lane], a2 = a[OUTF + lane];
    const float4* wrow4 = (const float4*)&sWt[lane * WPAD];  // lane's W row
    int r0 = wave * 4;                     // this wave's 4 rows
    const float4* sxr[4];
#pragma unroll
    for (int r = 0; r < 4; ++r) sxr[r] = (const float4*)&sx[(r0 + r) * INF];

    float acc[4] = {0.f, 0.f, 0.f, 0.f};
#pragma unroll
    for (int c4 = 0; c4 < INF / 4; ++c4) {
        float4 wv4 = wrow4[c4];            // per-lane b128 (read once)
#pragma unroll
        for (int r = 0; r < 4; ++r) {
            float4 xv = sxr[r][c4];        // broadcast (same addr across wave)
            acc[r] += xv.x * wv4.x + xv.y * wv4.y + xv.z * wv4.z + xv.w * wv4.w;
        }
    }
#pragma unroll
    for (int r = 0; r < 4; ++r) {
        int g = rowBase + r0 + r;
        int k = g >> 13;                   // g / NN
        int j = g & (NN - 1);              // g % NN
        float w1 = acc[r] * a1, w2 = acc[r] * a2;
#pragma unroll
        for (int off = 32; off; off >>= 1) {
            w1 += __shfl_down(w1, off);
            w2 += __shfl_down(w2, off);
        }
        float other = __shfl_xor(acc[r], 1);  // f=lane^1 partner
        if ((lane & 1) == 0) {
            __half2 hv = __halves2half2(__float2half(acc[r]), __float2half(other));
            ((__half2*)(WhI + (size_t)j * 128 + k * OUTF))[lane >> 1] = hv;
        }
        if (lane == 0) { Wh1[k * NN + j] = w1; W2I[j * KK + k] = w2; }
    }
}

// ---- Kernel 2: wave-per-row, barrier-free: scan+compact+softmax+gather ------
__global__ __launch_bounds__(256) void attn_kernel(
    const float* __restrict__ adj, const __half* __restrict__ WhI,
    const float* __restrict__ Wh1, const float* __restrict__ W2I,
    __half* __restrict__ hI, int* __restrict__ deg, int* __restrict__ nbrs)
{
    __shared__ int   s_idx[4][MAXD];          // 4 KB
    __shared__ float s_p0[4][MAXD];           // 4 KB
    __shared__ float s_p1[4][MAXD];           // 4 KB

    int tid = threadIdx.x, lane = tid & 63, wv = tid >> 6;
    int i = blockIdx.x * 4 + wv;
    const floatx4* row4 = (const floatx4*)(adj + (size_t)i * NN);

    // ---- Phase A: scan own row in 4 chunks of 8 dwordx4/lane, SW-pipelined
    floatx4 vA[8], vB[8];
#pragma unroll
    for (int it = 0; it < 8; ++it)
        vA[it] = __builtin_nontemporal_load(&row4[it * 64 + lane]);
    int base = 0;
#pragma unroll
    for (int c = 0; c < 4; ++c) {
        if (c < 3) {
#pragma unroll
            for (int it = 0; it < 8; ++it)
                vB[it] = __builtin_nontemporal_load(
                    &row4[(c + 1) * 512 + it * 64 + lane]);
        }
        unsigned int msk = 0;
#pragma unroll
        for (int it = 0; it < 8; ++it) {
            if (vA[it].x > 0.f) msk |= 1u << (it * 4 + 0);
            if (vA[it].y > 0.f) msk |= 1u << (it * 4 + 1);
            if (vA[it].z > 0.f) msk |= 1u << (it * 4 + 2);
            if (vA[it].w > 0.f) msk |= 1u << (it * 4 + 3);
        }
        int cnt = __popc(msk);
        int pre = cnt;                         // wave-inclusive prefix
#pragma unroll
        for (int off = 1; off < 64; off <<= 1) {
            int n = __shfl_up(pre, off);
            if (lane >= off) pre += n;
        }
        int tot = __shfl(pre, 63);
        int pos = base + pre - cnt;
        while (msk) {
            int b = __ffs(msk) - 1;
            msk &= msk - 1;
            if (pos < MAXD)
                s_idx[wv][pos] = (c * 512 + (b >> 2) * 64 + lane) * 4 + (b & 3);
            ++pos;
        }
        base += tot;
#pragma unroll
        for (int it = 0; it < 8; ++it) vA[it] = vB[it];
    }
    int d = min(base, MAXD);
    if (lane == 0) deg[i] = d;
    for (int t = lane; t < d; t += 64) nbrs[(size_t)i * MAXD + t] = s_idx[wv][t];

    // ---- Phase B: softmax over neighbors, wave-local (4 slots/lane) ----
    float wh1_0 = Wh1[i], wh1_1 = Wh1[NN + i];
    float e0[4], e1[4];
    float m0 = -1e30f, m1 = -1e30f;
#pragma unroll
    for (int s = 0; s < 4; ++s) {
        int t = lane + s * 64;
        e0[s] = -1e30f; e1[s] = -1e30f;
        if (t < d) {
            int j = s_idx[wv][t];
            float2 w2 = ((const float2*)W2I)[j];
            e0[s] = fmaxf(wh1_0 + w2.x, 0.f);
            e1[s] = fmaxf(wh1_1 + w2.y, 0.f);
        }
        m0 = fmaxf(m0, e0[s]); m1 = fmaxf(m1, e1[s]);
    }
#pragma unroll
    for (int off = 32; off; off >>= 1) {
        m0 = fmaxf(m0, __shfl_xor(m0, off));
        m1 = fmaxf(m1, __shfl_xor(m1, off));
    }
    float sum0 = 0.f, sum1 = 0.f;
#pragma unroll
    for (int s = 0; s < 4; ++s) {
        int t = lane + s * 64;
        if (t < d) {
            float p0 = __expf(e0[s] - m0), p1 = __expf(e1[s] - m1);
            s_p0[wv][t] = p0; s_p1[wv][t] = p1;
            sum0 += p0; sum1 += p1;
        }
    }
#pragma unroll
    for (int off = 32; off; off >>= 1) {
        sum0 += __shfl_xor(sum0, off);
        sum1 += __shfl_xor(sum1, off);
    }
    float inv0 = sum0 > 0.f ? 1.f / sum0 : 0.f;
    float inv1 = sum1 > 0.f ? 1.f / sum1 : 0.f;

    // ---- Phase C: h'[i, 2h..2h+1] = sum_t p[k][t] * WhI[j_t, 2h..2h+1] ----
    int h = lane;                              // half2 col; k = h>>5
    const float* pk = (h & 32) ? s_p1[wv] : s_p0[wv];
    const __half2* Wb = (const __half2*)WhI + h;
    float2 acc = {0.f, 0.f};
    int t = 0;
    for (; t + 15 < d; t += 16) {
        int jj[16]; float q[16]; float2 w[16];
#pragma unroll
        for (int u = 0; u < 16; ++u) { jj[u] = s_idx[wv][t + u]; q[u] = pk[t + u]; }
#pragma unroll
        for (int u = 0; u < 16; ++u) w[u] = __half22float2(Wb[(size_t)jj[u] * 64]);
#pragma unroll
        for (int u = 0; u < 16; ++u) { acc.x += q[u] * w[u].x; acc.y += q[u] * w[u].y; }
    }
    for (; t + 3 < d; t += 4) {
        int jj[4]; float q[4]; float2 w[4];
#pragma unroll
        for (int u = 0; u < 4; ++u) { jj[u] = s_idx[wv][t + u]; q[u] = pk[t + u]; }
#pragma unroll
        for (int u = 0; u < 4; ++u) w[u] = __half22float2(Wb[(size_t)jj[u] * 64]);
#pragma unroll
        for (int u = 0; u < 4; ++u) { acc.x += q[u] * w[u].x; acc.y += q[u] * w[u].y; }
    }
    for (; t < d; ++t) {
        float2 w = __half22float2(Wb[(size_t)s_idx[wv][t] * 64]);
        float q = pk[t];
        acc.x += q * w.x; acc.y += q * w.y;
    }
    float inv = (h & 32) ? inv1 : inv0;
    float2 r = { acc.x * inv, acc.y * inv };
    ((__half2*)hI)[(size_t)i * 64 + h] = __float22half2_rn(r);
}

// ---- Kernel 3: out = relu(adj @ h'), wave-per-row via CSR, barrier-free ----
__global__ __launch_bounds__(256) void spmm_kernel(
    const __half* __restrict__ hI, const int* __restrict__ deg,
    const int* __restrict__ nbrs, float* __restrict__ out)
{
    __shared__ int s_idx[4][MAXD];
    int tid = threadIdx.x, lane = tid & 63, wv = tid >> 6;
    int i = blockIdx.x * 4 + wv;
    int d = deg[i];
    for (int t = lane; t < d; t += 64) s_idx[wv][t] = nbrs[(size_t)i * MAXD + t];

    int h = lane;
    const __half2* hb = (const __half2*)hI + h;
    float2 acc = {0.f, 0.f};
    int t = 0;
    for (; t + 15 < d; t += 16) {
        int jj[16]; float2 w[16];
#pragma unroll
        for (int u = 0; u < 16; ++u) jj[u] = s_idx[wv][t + u];
#pragma unroll
        for (int u = 0; u < 16; ++u) w[u] = __half22float2(hb[(size_t)jj[u] * 64]);
#pragma unroll
        for (int u = 0; u < 16; ++u) { acc.x += w[u].x; acc.y += w[u].y; }
    }
    for (; t < d; ++t) {
        float2 w = __half22float2(hb[(size_t)s_idx[wv][t] * 64]);
        acc.x += w.x; acc.y += w.y;
    }
    int k = h >> 5;
    float2 r = { fmaxf(acc.x, 0.f), fmaxf(acc.y, 0.f) };
    ((float2*)(out + ((size_t)k * NN + i) * OUTF))[h & 31] = r;
}

extern "C" void kernel_launch(void* const* d_in, const int* in_sizes, int n_in,
                              void* d_out, int out_size, void* d_ws, size_t ws_size,
                              hipStream_t stream) {
    const float* x      = (const float*)d_in[0];   // [2, 8192, 128]
    const float* adj    = (const float*)d_in[1];   // [8192, 8192]
    const float* weight = (const float*)d_in[2];   // [128, 64]
    const float* a      = (const float*)d_in[3];   // [128, 1]
    float* out = (float*)d_out;                    // [2, 8192, 64] fp32

    // ws layout: WhI fp16 [N][128] (2 MB) | hI fp16 [N][128] (2 MB)
    //            Wh1 fp32 [2][N] | W2I fp32 [N][2] | deg [N] | nbrs [N][MAXD]
    __half* WhI = (__half*)d_ws;
    __half* hI  = WhI + (size_t)NN * 128;
    float*  Wh1 = (float*)(hI + (size_t)NN * 128);
    float*  W2I = Wh1 + NROWS;
    int*    deg = (int*)(W2I + (size_t)NN * KK);
    int*    nbrs = deg + NN;

    wh_kernel<<<NROWS / WH_RPB, 256, 0, stream>>>(x, weight, a, WhI, Wh1, W2I);
    attn_kernel<<<NN / 4, 256, 0, stream>>>(adj, WhI, Wh1, W2I, hI, deg, nbrs);
    spmm_kernel<<<NN / 4, 256, 0, stream>>>(hI, deg, nbrs, out);
}

// Round 9
// 385.644 us; speedup vs baseline: 1.0904x; 1.0904x over previous
//
#include <hip/hip_runtime.h>
#include <hip/hip_fp16.h>

#define NN 8192
#define INF 128
#define OUTF 64
#define KK 2
#define NROWS (KK * NN)
#define MAXD 256
#define WH_RPB 16
#define WPAD 130

typedef float floatx4 __attribute__((ext_vector_type(4)));

// ---- Kernel 1: Wh = x@W -> WhI fp16 [j][k*64+f]; Wh1 fp32 [k][N]; W2I fp32 [j][k]
// NOTE: scalar wrow reads on purpose — R8's float4 view of sWt rows was
// 8B-misaligned for odd lanes (WPAD=130 floats -> lane*520 B) and regressed 12%.
__global__ __launch_bounds__(256) void wh_kernel(
    const float* __restrict__ x, const float* __restrict__ weight,
    const float* __restrict__ a,
    __half* __restrict__ WhI, float* __restrict__ Wh1, float* __restrict__ W2I)
{
    __shared__ float sWt[OUTF * WPAD];     // transposed W: [f][c], pad 130 (33 KB)
    __shared__ float sx[WH_RPB * INF];     // 8 KB
    int tid = threadIdx.x;
    for (int idx = tid; idx < INF * OUTF; idx += 256) {
        int c = idx >> 6, f = idx & 63;    // weight[c][f] row-major [128][64]
        sWt[f * WPAD + c] = weight[idx];
    }
    int rowBase = blockIdx.x * WH_RPB;     // global row in [0, 16384)
    const float4* xb = (const float4*)(x + (size_t)rowBase * INF);
#pragma unroll
    for (int idx = tid; idx < (WH_RPB * INF) / 4; idx += 256)
        ((float4*)sx)[idx] = xb[idx];
    __syncthreads();

    int wave = tid >> 6, lane = tid & 63;
    float a1 = a[lane], a2 = a[OUTF + lane];
    const float* wrow = &sWt[lane * WPAD]; // lane's own contiguous weight row
    for (int r = wave; r < WH_RPB; r += 4) {
        const float4* sx4 = (const float4*)&sx[r * INF];
        float acc = 0.f;
#pragma unroll
        for (int c4 = 0; c4 < INF / 4; ++c4) {
            float4 xv = sx4[c4];
            acc += xv.x * wrow[c4 * 4 + 0] + xv.y * wrow[c4 * 4 + 1]
                 + xv.z * wrow[c4 * 4 + 2] + xv.w * wrow[c4 * 4 + 3];
        }
        int g = rowBase + r;
        int k = g >> 13;                   // g / NN
        int j = g & (NN - 1);              // g % NN
        float w1 = acc * a1, w2 = acc * a2;
#pragma unroll
        for (int off = 32; off; off >>= 1) {
            w1 += __shfl_down(w1, off);
            w2 += __shfl_down(w2, off);
        }
        float other = __shfl_xor(acc, 1);  // f=lane^1 partner
        if ((lane & 1) == 0) {
            __half2 hv = __halves2half2(__float2half(acc), __float2half(other));
            ((__half2*)(WhI + (size_t)j * 128 + k * OUTF))[lane >> 1] = hv;
        }
        if (lane == 0) { Wh1[k * NN + j] = w1; W2I[j * KK + k] = w2; }
    }
}

// ---- Kernel 2: wave-per-row, barrier-free: scan+compact+softmax+gather ------
__global__ __launch_bounds__(256) void attn_kernel(
    const float* __restrict__ adj, const __half* __restrict__ WhI,
    const float* __restrict__ Wh1, const float* __restrict__ W2I,
    __half* __restrict__ hI, int* __restrict__ deg, int* __restrict__ nbrs)
{
    __shared__ int   s_idx[4][MAXD];          // 4 KB
    __shared__ float s_p0[4][MAXD];           // 4 KB
    __shared__ float s_p1[4][MAXD];           // 4 KB

    int tid = threadIdx.x, lane = tid & 63, wv = tid >> 6;
    int i = blockIdx.x * 4 + wv;
    const floatx4* row4 = (const floatx4*)(adj + (size_t)i * NN);

    // ---- Phase A: scan own row in 4 chunks of 8 dwordx4/lane, SW-pipelined
    floatx4 vA[8], vB[8];
#pragma unroll
    for (int it = 0; it < 8; ++it)
        vA[it] = __builtin_nontemporal_load(&row4[it * 64 + lane]);
    int base = 0;
#pragma unroll
    for (int c = 0; c < 4; ++c) {
        if (c < 3) {
#pragma unroll
            for (int it = 0; it < 8; ++it)
                vB[it] = __builtin_nontemporal_load(
                    &row4[(c + 1) * 512 + it * 64 + lane]);
        }
        unsigned int msk = 0;
#pragma unroll
        for (int it = 0; it < 8; ++it) {
            if (vA[it].x > 0.f) msk |= 1u << (it * 4 + 0);
            if (vA[it].y > 0.f) msk |= 1u << (it * 4 + 1);
            if (vA[it].z > 0.f) msk |= 1u << (it * 4 + 2);
            if (vA[it].w > 0.f) msk |= 1u << (it * 4 + 3);
        }
        int cnt = __popc(msk);
        int pre = cnt;                         // wave-inclusive prefix
#pragma unroll
        for (int off = 1; off < 64; off <<= 1) {
            int n = __shfl_up(pre, off);
            if (lane >= off) pre += n;
        }
        int tot = __shfl(pre, 63);
        int pos = base + pre - cnt;
        while (msk) {
            int b = __ffs(msk) - 1;
            msk &= msk - 1;
            if (pos < MAXD)
                s_idx[wv][pos] = (c * 512 + (b >> 2) * 64 + lane) * 4 + (b & 3);
            ++pos;
        }
        base += tot;
#pragma unroll
        for (int it = 0; it < 8; ++it) vA[it] = vB[it];
    }
    int d = min(base, MAXD);
    if (lane == 0) deg[i] = d;
    for (int t = lane; t < d; t += 64) nbrs[(size_t)i * MAXD + t] = s_idx[wv][t];

    // ---- Phase B: softmax over neighbors, wave-local (4 slots/lane) ----
    float wh1_0 = Wh1[i], wh1_1 = Wh1[NN + i];
    float e0[4], e1[4];
    float m0 = -1e30f, m1 = -1e30f;
#pragma unroll
    for (int s = 0; s < 4; ++s) {
        int t = lane + s * 64;
        e0[s] = -1e30f; e1[s] = -1e30f;
        if (t < d) {
            int j = s_idx[wv][t];
            float2 w2 = ((const float2*)W2I)[j];
            e0[s] = fmaxf(wh1_0 + w2.x, 0.f);
            e1[s] = fmaxf(wh1_1 + w2.y, 0.f);
        }
        m0 = fmaxf(m0, e0[s]); m1 = fmaxf(m1, e1[s]);
    }
#pragma unroll
    for (int off = 32; off; off >>= 1) {
        m0 = fmaxf(m0, __shfl_xor(m0, off));
        m1 = fmaxf(m1, __shfl_xor(m1, off));
    }
    float sum0 = 0.f, sum1 = 0.f;
#pragma unroll
    for (int s = 0; s < 4; ++s) {
        int t = lane + s * 64;
        if (t < d) {
            float p0 = __expf(e0[s] - m0), p1 = __expf(e1[s] - m1);
            s_p0[wv][t] = p0; s_p1[wv][t] = p1;
            sum0 += p0; sum1 += p1;
        }
    }
#pragma unroll
    for (int off = 32; off; off >>= 1) {
        sum0 += __shfl_xor(sum0, off);
        sum1 += __shfl_xor(sum1, off);
    }
    float inv0 = sum0 > 0.f ? 1.f / sum0 : 0.f;
    float inv1 = sum1 > 0.f ? 1.f / sum1 : 0.f;

    // ---- Phase C: h'[i, 2h..2h+1] = sum_t p[k][t] * WhI[j_t, 2h..2h+1] ----
    int h = lane;                              // half2 col; k = h>>5
    const float* pk = (h & 32) ? s_p1[wv] : s_p0[wv];
    const __half2* Wb = (const __half2*)WhI + h;
    float2 acc = {0.f, 0.f};
    int t = 0;
    for (; t + 15 < d; t += 16) {
        int jj[16]; float q[16]; float2 w[16];
#pragma unroll
        for (int u = 0; u < 16; ++u) { jj[u] = s_idx[wv][t + u]; q[u] = pk[t + u]; }
#pragma unroll
        for (int u = 0; u < 16; ++u) w[u] = __half22float2(Wb[(size_t)jj[u] * 64]);
#pragma unroll
        for (int u = 0; u < 16; ++u) { acc.x += q[u] * w[u].x; acc.y += q[u] * w[u].y; }
    }
    for (; t + 3 < d; t += 4) {
        int jj[4]; float q[4]; float2 w[4];
#pragma unroll
        for (int u = 0; u < 4; ++u) { jj[u] = s_idx[wv][t + u]; q[u] = pk[t + u]; }
#pragma unroll
        for (int u = 0; u < 4; ++u) w[u] = __half22float2(Wb[(size_t)jj[u] * 64]);
#pragma unroll
        for (int u = 0; u < 4; ++u) { acc.x += q[u] * w[u].x; acc.y += q[u] * w[u].y; }
    }
    for (; t < d; ++t) {
        float2 w = __half22float2(Wb[(size_t)s_idx[wv][t] * 64]);
        float q = pk[t];
        acc.x += q * w.x; acc.y += q * w.y;
    }
    float inv = (h & 32) ? inv1 : inv0;
    float2 r = { acc.x * inv, acc.y * inv };
    ((__half2*)hI)[(size_t)i * 64 + h] = __float22half2_rn(r);
}

// ---- Kernel 3: out = relu(adj @ h'), wave-per-row via CSR, barrier-free ----
__global__ __launch_bounds__(256) void spmm_kernel(
    const __half* __restrict__ hI, const int* __restrict__ deg,
    const int* __restrict__ nbrs, float* __restrict__ out)
{
    __shared__ int s_idx[4][MAXD];
    int tid = threadIdx.x, lane = tid & 63, wv = tid >> 6;
    int i = blockIdx.x * 4 + wv;
    int d = deg[i];
    for (int t = lane; t < d; t += 64) s_idx[wv][t] = nbrs[(size_t)i * MAXD + t];

    int h = lane;
    const __half2* hb = (const __half2*)hI + h;
    float2 acc = {0.f, 0.f};
    int t = 0;
    for (; t + 15 < d; t += 16) {
        int jj[16]; float2 w[16];
#pragma unroll
        for (int u = 0; u < 16; ++u) jj[u] = s_idx[wv][t + u];
#pragma unroll
        for (int u = 0; u < 16; ++u) w[u] = __half22float2(hb[(size_t)jj[u] * 64]);
#pragma unroll
        for (int u = 0; u < 16; ++u) { acc.x += w[u].x; acc.y += w[u].y; }
    }
    for (; t < d; ++t) {
        float2 w = __half22float2(hb[(size_t)s_idx[wv][t] * 64]);
        acc.x += w.x; acc.y += w.y;
    }
    int k = h >> 5;
    float2 r = { fmaxf(acc.x, 0.f), fmaxf(acc.y, 0.f) };
    ((float2*)(out + ((size_t)k * NN + i) * OUTF))[h & 31] = r;
}

extern "C" void kernel_launch(void* const* d_in, const int* in_sizes, int n_in,
                              void* d_out, int out_size, void* d_ws, size_t ws_size,
                              hipStream_t stream) {
    const float* x      = (const float*)d_in[0];   // [2, 8192, 128]
    const float* adj    = (const float*)d_in[1];   // [8192, 8192]
    const float* weight = (const float*)d_in[2];   // [128, 64]
    const float* a      = (const float*)d_in[3];   // [128, 1]
    float* out = (float*)d_out;                    // [2, 8192, 64] fp32

    // ws layout: WhI fp16 [N][128] (2 MB) | hI fp16 [N][128] (2 MB)
    //            Wh1 fp32 [2][N] | W2I fp32 [N][2] | deg [N] | nbrs [N][MAXD]
    __half* WhI = (__half*)d_ws;
    __half* hI  = WhI + (size_t)NN * 128;
    float*  Wh1 = (float*)(hI + (size_t)NN * 128);
    float*  W2I = Wh1 + NROWS;
    int*    deg = (int*)(W2I + (size_t)NN * KK);
    int*    nbrs = deg + NN;

    wh_kernel<<<NROWS / WH_RPB, 256, 0, stream>>>(x, weight, a, WhI, Wh1, W2I);
    attn_kernel<<<NN / 4, 256, 0, stream>>>(adj, WhI, Wh1, W2I, hI, deg, nbrs);
    spmm_kernel<<<NN / 4, 256, 0, stream>>>(hI, deg, nbrs, out);
}